// Round 6
// baseline (3002.108 us; speedup 1.0000x reference)
//
#include <hip/hip_runtime.h>
#include <math.h>

#define EPSBN 1e-5f

// sums layout in d_ws (floats), replicated in NSLOT slots of stride SUMSTRIDE:
// 0: s1[16], 16: q1[16], 32: s2[16], 48: q2[16], 64: s3[12], 76: q3[12],
// 88: s4[12], 100: q4[12], 112: s5[8], 120: q5[8]   -> 128 floats per slot
constexpr int NSLOT = 8;
constexpr int SUMSTRIDE = 128;

struct P {
  const float* in;
  const float *w1,*b1,*g1,*be1;
  const float *w2,*b2,*g2,*be2;
  const float *w3,*b3,*g3,*be3;
  const float *w4,*b4,*g4,*be4;
  const float *w5,*b5,*g5,*be5;
  const float *w6,*b6;
  float* out;
  float* sums;
  int B;
};

__device__ inline float slot_sum(const float* base) {
  float s = 0.f;
  #pragma unroll
  for (int k = 0; k < NSLOT; ++k) s += base[k * SUMSTRIDE];
  return s;
}

template<int OUT, int IN>
__device__ inline void ld_raw(float* sw, float* sb, const float* __restrict__ w,
                              const float* __restrict__ b) {
  for (int t = threadIdx.x; t < OUT * IN; t += 256) sw[t] = w[t];
  if (threadIdx.x < OUT) sb[threadIdx.x] = b[threadIdx.x];
}

template<int OUT, int IN>
__device__ inline void ld_fold(float* sw, float* sb, const float* __restrict__ w,
                               const float* __restrict__ b, const float* __restrict__ g,
                               const float* __restrict__ be, const float* sum,
                               const float* sq, float invB) {
  for (int o = threadIdx.x; o < OUT; o += 256) {
    float m = slot_sum(sum + o) * invB;
    float v = slot_sum(sq + o) * invB - m * m;
    float a = g[o] * rsqrtf(v + EPSBN);
    float c = be[o] - a * m;
    sb[o] = fmaf(a, b[o], c);
  }
  for (int t = threadIdx.x; t < OUT * IN; t += 256) {
    int o = t / IN;
    float m = slot_sum(sum + o) * invB;
    float v = slot_sum(sq + o) * invB - m * m;
    float a = g[o] * rsqrtf(v + EPSBN);
    sw[t] = a * w[t];
  }
}

template<int N>
__device__ inline void accum1(const float (&h)[N], float* accS, float* accQ) {
  #pragma unroll
  for (int o = 0; o < N; ++o) {
    accS[o] += h[o];
    accQ[o] = fmaf(h[o], h[o], accQ[o]);
  }
}

template<int STAGE>
__global__ __launch_bounds__(256)
void qcnn(P p) {
  __shared__ float sW1[128], sB1[16];
  __shared__ float sW2[256], sB2[16];
  __shared__ float sW3[192], sB3[12];
  __shared__ float sW4[144], sB4[12];
  __shared__ float sW5[96],  sB5[8];
  __shared__ float sW6[8],   sB6[1];
  __shared__ float red[4][32];

  const float invB = 1.0f / (float)p.B;
  if constexpr (STAGE == 1) ld_raw<16,8>(sW1, sB1, p.w1, p.b1);
  else ld_fold<16,8>(sW1, sB1, p.w1, p.b1, p.g1, p.be1, p.sums + 0, p.sums + 16, invB);
  if constexpr (STAGE >= 2) {
    if constexpr (STAGE == 2) ld_raw<16,16>(sW2, sB2, p.w2, p.b2);
    else ld_fold<16,16>(sW2, sB2, p.w2, p.b2, p.g2, p.be2, p.sums + 32, p.sums + 48, invB);
  }
  if constexpr (STAGE >= 3) {
    if constexpr (STAGE == 3) ld_raw<12,16>(sW3, sB3, p.w3, p.b3);
    else ld_fold<12,16>(sW3, sB3, p.w3, p.b3, p.g3, p.be3, p.sums + 64, p.sums + 76, invB);
  }
  if constexpr (STAGE >= 4) {
    if constexpr (STAGE == 4) ld_raw<12,12>(sW4, sB4, p.w4, p.b4);
    else ld_fold<12,12>(sW4, sB4, p.w4, p.b4, p.g4, p.be4, p.sums + 88, p.sums + 100, invB);
  }
  if constexpr (STAGE >= 5) {
    if constexpr (STAGE == 5) ld_raw<8,12>(sW5, sB5, p.w5, p.b5);
    else ld_fold<8,12>(sW5, sB5, p.w5, p.b5, p.g5, p.be5, p.sums + 112, p.sums + 120, invB);
  }
  if constexpr (STAGE == 6) ld_raw<1,8>(sW6, sB6, p.w6, p.b6);
  __syncthreads();

  constexpr int W   = (STAGE <= 2) ? 16 : (STAGE <= 4) ? 12 : 8;   // stats width
  constexpr int OFF = (STAGE == 1) ? 0 : (STAGE == 2) ? 32 : (STAGE == 3) ? 64
                    : (STAGE == 4) ? 88 : 112;

  float accS[16], accQ[16];
  if constexpr (STAGE <= 5) {
    #pragma unroll
    for (int i = 0; i < 16; ++i) { accS[i] = 0.f; accQ[i] = 0.f; }
  }

  const int tid = blockIdx.x * 256 + threadIdx.x;
  const int nthreads = gridDim.x * 256;

  for (int row = tid; row < p.B; row += nthreads) {
    // one row of input: 8 floats = 32B contiguous per thread (2x float4)
    float x[8];
    const float4* ip = reinterpret_cast<const float4*>(p.in) + (size_t)row * 2;
    float4 u0 = ip[0], u1 = ip[1];
    x[0] = u0.x; x[1] = u0.y; x[2] = u0.z; x[3] = u0.w;
    x[4] = u1.x; x[5] = u1.y; x[6] = u1.z; x[7] = u1.w;

    float h1[16];
    #pragma unroll
    for (int o = 0; o < 16; ++o) {
      float s = sB1[o];
      #pragma unroll
      for (int i = 0; i < 8; ++i) s = fmaf(sW1[o * 8 + i], x[i], s);
      h1[o] = s;
    }
    if constexpr (STAGE == 1) { accum1<16>(h1, accS, accQ); }
    else {
      float x1[16];
      #pragma unroll
      for (int o = 0; o < 16; ++o) x1[o] = fmaxf(h1[o], 0.f);

      float h2[16];
      #pragma unroll
      for (int o = 0; o < 16; ++o) {
        float s = sB2[o];
        #pragma unroll
        for (int i = 0; i < 16; ++i) s = fmaf(sW2[o * 16 + i], x1[i], s);
        h2[o] = s;
      }
      if constexpr (STAGE == 2) { accum1<16>(h2, accS, accQ); }
      else {
        // x2 = relu(relu(h2) + x1); outer relu redundant (both terms >= 0)
        float x2[16];
        #pragma unroll
        for (int o = 0; o < 16; ++o) x2[o] = fmaxf(h2[o], 0.f) + x1[o];

        float h3[12];
        #pragma unroll
        for (int o = 0; o < 12; ++o) {
          float s = sB3[o];
          #pragma unroll
          for (int i = 0; i < 16; ++i) s = fmaf(sW3[o * 16 + i], x2[i], s);
          h3[o] = s;
        }
        if constexpr (STAGE == 3) { accum1<12>(h3, accS, accQ); }
        else {
          float x3[12];
          #pragma unroll
          for (int o = 0; o < 12; ++o) x3[o] = fmaxf(h3[o], 0.f);

          float h4[12];
          #pragma unroll
          for (int o = 0; o < 12; ++o) {
            float s = sB4[o];
            #pragma unroll
            for (int i = 0; i < 12; ++i) s = fmaf(sW4[o * 12 + i], x3[i], s);
            h4[o] = s;
          }
          if constexpr (STAGE == 4) { accum1<12>(h4, accS, accQ); }
          else {
            float x4[12];
            #pragma unroll
            for (int o = 0; o < 12; ++o) x4[o] = fmaxf(h4[o], 0.f) + x3[o];

            float h5[8];
            #pragma unroll
            for (int o = 0; o < 8; ++o) {
              float s = sB5[o];
              #pragma unroll
              for (int i = 0; i < 12; ++i) s = fmaf(sW5[o * 12 + i], x4[i], s);
              h5[o] = s;
            }
            if constexpr (STAGE == 5) { accum1<8>(h5, accS, accQ); }
            else {
              float z = sB6[0];
              #pragma unroll
              for (int i = 0; i < 8; ++i) z = fmaf(sW6[i], fmaxf(h5[i], 0.f), z);
              p.out[row] = 1.0f / (1.0f + expf(-z));
            }
          }
        }
      }
    }
  }

  if constexpr (STAGE <= 5) {
    const int lane = threadIdx.x & 63;
    const int wv = threadIdx.x >> 6;
    #pragma unroll
    for (int v = 0; v < 2 * W; ++v) {
      float val = (v < W) ? accS[v] : accQ[v - W];
      #pragma unroll
      for (int d = 1; d < 64; d <<= 1) val += __shfl_xor(val, d, 64);
      if (lane == 0) red[wv][v] = val;
    }
    __syncthreads();
    if (threadIdx.x < 2 * W) {
      float f = red[0][threadIdx.x] + red[1][threadIdx.x] +
                red[2][threadIdx.x] + red[3][threadIdx.x];
      const int slot = blockIdx.x & (NSLOT - 1);
      atomicAdd(p.sums + slot * SUMSTRIDE + OFF + threadIdx.x, f);
    }
  }
}

extern "C" void kernel_launch(void* const* d_in, const int* in_sizes, int n_in,
                              void* d_out, int out_size, void* d_ws, size_t ws_size,
                              hipStream_t stream) {
  P p;
  p.in  = (const float*)d_in[0];
  p.w1 = (const float*)d_in[1];  p.b1 = (const float*)d_in[2];
  p.g1 = (const float*)d_in[3];  p.be1 = (const float*)d_in[4];
  p.w2 = (const float*)d_in[5];  p.b2 = (const float*)d_in[6];
  p.g2 = (const float*)d_in[7];  p.be2 = (const float*)d_in[8];
  p.w3 = (const float*)d_in[9];  p.b3 = (const float*)d_in[10];
  p.g3 = (const float*)d_in[11]; p.be3 = (const float*)d_in[12];
  p.w4 = (const float*)d_in[13]; p.b4 = (const float*)d_in[14];
  p.g4 = (const float*)d_in[15]; p.be4 = (const float*)d_in[16];
  p.w5 = (const float*)d_in[17]; p.b5 = (const float*)d_in[18];
  p.g5 = (const float*)d_in[19]; p.be5 = (const float*)d_in[20];
  p.w6 = (const float*)d_in[21]; p.b6 = (const float*)d_in[22];
  p.out = (float*)d_out;
  p.sums = (float*)d_ws;
  p.B = in_sizes[0] / 8;

  hipMemsetAsync(d_ws, 0, NSLOT * SUMSTRIDE * sizeof(float), stream);

  const dim3 grid(2048), block(256);
  qcnn<1><<<grid, block, 0, stream>>>(p);
  qcnn<2><<<grid, block, 0, stream>>>(p);
  qcnn<3><<<grid, block, 0, stream>>>(p);
  qcnn<4><<<grid, block, 0, stream>>>(p);
  qcnn<5><<<grid, block, 0, stream>>>(p);
  qcnn<6><<<grid, block, 0, stream>>>(p);
}

// Round 11
// 660.424 us; speedup vs baseline: 4.5457x; 4.5457x over previous
//
#include <hip/hip_runtime.h>
#include <math.h>

#define EPSBN 1e-5f

// sums layout in d_ws (floats), replicated in NSLOT slots of stride SUMSTRIDE:
// 0: s1[16], 16: q1[16], 32: s2[16], 48: q2[16], 64: s3[12], 76: q3[12],
// 88: s4[12], 100: q4[12], 112: s5[8], 120: q5[8]   -> 128 floats per slot
constexpr int NSLOT = 8;
constexpr int SUMSTRIDE = 128;

struct P {
  const float* in;
  const float *w1,*b1,*g1,*be1;
  const float *w2,*b2,*g2,*be2;
  const float *w3,*b3,*g3,*be3;
  const float *w4,*b4,*g4,*be4;
  const float *w5,*b5,*g5,*be5;
  const float *w6,*b6;
  float* out;
  float* sums;
  int B;
};

__device__ inline float slot_sum(const float* base) {
  float s = 0.f;
  #pragma unroll
  for (int k = 0; k < NSLOT; ++k) s += base[k * SUMSTRIDE];
  return s;
}

template<int OUT, int IN>
__device__ inline void ld_raw(float* sw, float* sb, const float* __restrict__ w,
                              const float* __restrict__ b) {
  for (int t = threadIdx.x; t < OUT * IN; t += 256) sw[t] = w[t];
  if (threadIdx.x < OUT) sb[threadIdx.x] = b[threadIdx.x];
}

template<int OUT, int IN>
__device__ inline void ld_fold(float* sw, float* sb, const float* __restrict__ w,
                               const float* __restrict__ b, const float* __restrict__ g,
                               const float* __restrict__ be, const float* sum,
                               const float* sq, float invB) {
  for (int o = threadIdx.x; o < OUT; o += 256) {
    float m = slot_sum(sum + o) * invB;
    float v = slot_sum(sq + o) * invB - m * m;
    float a = g[o] * rsqrtf(v + EPSBN);
    float c = be[o] - a * m;
    sb[o] = fmaf(a, b[o], c);
  }
  for (int t = threadIdx.x; t < OUT * IN; t += 256) {
    int o = t / IN;
    float m = slot_sum(sum + o) * invB;
    float v = slot_sum(sq + o) * invB - m * m;
    float a = g[o] * rsqrtf(v + EPSBN);
    sw[t] = a * w[t];
  }
}

template<int N>
__device__ inline void accum1(const float (&h)[N], float (&aS)[16], float (&aQ)[16]) {
  #pragma unroll
  for (int o = 0; o < N; ++o) {
    aS[o] += h[o];
    aQ[o] = fmaf(h[o], h[o], aQ[o]);
  }
}

template<int STAGE>
__global__ __launch_bounds__(256, 4)   // 4 wg/CU -> <=128 VGPR: no spill headroom games
void qcnn(P p) {
  __shared__ alignas(16) float sW1[128], sB1[16];
  __shared__ alignas(16) float sW2[256], sB2[16];
  __shared__ alignas(16) float sW3[192], sB3[12];
  __shared__ alignas(16) float sW4[144], sB4[12];
  __shared__ alignas(16) float sW5[96],  sB5[8];
  __shared__ alignas(16) float sW6[8],   sB6[1];
  __shared__ float red[4][32];

  const float invB = 1.0f / (float)p.B;
  if constexpr (STAGE == 1) ld_raw<16,8>(sW1, sB1, p.w1, p.b1);
  else ld_fold<16,8>(sW1, sB1, p.w1, p.b1, p.g1, p.be1, p.sums + 0, p.sums + 16, invB);
  if constexpr (STAGE >= 2) {
    if constexpr (STAGE == 2) ld_raw<16,16>(sW2, sB2, p.w2, p.b2);
    else ld_fold<16,16>(sW2, sB2, p.w2, p.b2, p.g2, p.be2, p.sums + 32, p.sums + 48, invB);
  }
  if constexpr (STAGE >= 3) {
    if constexpr (STAGE == 3) ld_raw<12,16>(sW3, sB3, p.w3, p.b3);
    else ld_fold<12,16>(sW3, sB3, p.w3, p.b3, p.g3, p.be3, p.sums + 64, p.sums + 76, invB);
  }
  if constexpr (STAGE >= 4) {
    if constexpr (STAGE == 4) ld_raw<12,12>(sW4, sB4, p.w4, p.b4);
    else ld_fold<12,12>(sW4, sB4, p.w4, p.b4, p.g4, p.be4, p.sums + 88, p.sums + 100, invB);
  }
  if constexpr (STAGE >= 5) {
    if constexpr (STAGE == 5) ld_raw<8,12>(sW5, sB5, p.w5, p.b5);
    else ld_fold<8,12>(sW5, sB5, p.w5, p.b5, p.g5, p.be5, p.sums + 112, p.sums + 120, invB);
  }
  if constexpr (STAGE == 6) ld_raw<1,8>(sW6, sB6, p.w6, p.b6);
  __syncthreads();

  constexpr int W   = (STAGE <= 2) ? 16 : (STAGE <= 4) ? 12 : 8;   // stats width
  constexpr int OFF = (STAGE == 1) ? 0 : (STAGE == 2) ? 32 : (STAGE == 3) ? 64
                    : (STAGE == 4) ? 88 : 112;

  float accS[16], accQ[16];
  if constexpr (STAGE <= 5) {
    #pragma unroll
    for (int i = 0; i < 16; ++i) { accS[i] = 0.f; accQ[i] = 0.f; }
  }

  // exactly one row per thread: no row loop => nothing for LICM to hoist
  const int row = blockIdx.x * 256 + threadIdx.x;
  if (row < p.B) {
    float x[8];
    const float4* ip = reinterpret_cast<const float4*>(p.in) + (size_t)row * 2;
    float4 u0 = ip[0], u1 = ip[1];
    x[0] = u0.x; x[1] = u0.y; x[2] = u0.z; x[3] = u0.w;
    x[4] = u1.x; x[5] = u1.y; x[6] = u1.z; x[7] = u1.w;

    float h1[16];
    #pragma unroll
    for (int o = 0; o < 16; ++o) {
      float s = sB1[o];
      #pragma unroll
      for (int i = 0; i < 8; ++i) s = fmaf(sW1[o * 8 + i], x[i], s);
      h1[o] = s;
    }
    if constexpr (STAGE == 1) { accum1<16>(h1, accS, accQ); }
    else {
      float x1[16];
      #pragma unroll
      for (int o = 0; o < 16; ++o) x1[o] = fmaxf(h1[o], 0.f);

      float h2[16];
      #pragma unroll
      for (int o = 0; o < 16; ++o) {
        float s = sB2[o];
        #pragma unroll
        for (int i = 0; i < 16; ++i) s = fmaf(sW2[o * 16 + i], x1[i], s);
        h2[o] = s;
      }
      if constexpr (STAGE == 2) { accum1<16>(h2, accS, accQ); }
      else {
        // x2 = relu(relu(h2) + x1); outer relu redundant (both terms >= 0)
        float x2[16];
        #pragma unroll
        for (int o = 0; o < 16; ++o) x2[o] = fmaxf(h2[o], 0.f) + x1[o];

        float h3[12];
        #pragma unroll
        for (int o = 0; o < 12; ++o) {
          float s = sB3[o];
          #pragma unroll
          for (int i = 0; i < 16; ++i) s = fmaf(sW3[o * 16 + i], x2[i], s);
          h3[o] = s;
        }
        if constexpr (STAGE == 3) { accum1<12>(h3, accS, accQ); }
        else {
          float x3[12];
          #pragma unroll
          for (int o = 0; o < 12; ++o) x3[o] = fmaxf(h3[o], 0.f);

          float h4[12];
          #pragma unroll
          for (int o = 0; o < 12; ++o) {
            float s = sB4[o];
            #pragma unroll
            for (int i = 0; i < 12; ++i) s = fmaf(sW4[o * 12 + i], x3[i], s);
            h4[o] = s;
          }
          if constexpr (STAGE == 4) { accum1<12>(h4, accS, accQ); }
          else {
            float x4[12];
            #pragma unroll
            for (int o = 0; o < 12; ++o) x4[o] = fmaxf(h4[o], 0.f) + x3[o];

            float h5[8];
            #pragma unroll
            for (int o = 0; o < 8; ++o) {
              float s = sB5[o];
              #pragma unroll
              for (int i = 0; i < 12; ++i) s = fmaf(sW5[o * 12 + i], x4[i], s);
              h5[o] = s;
            }
            if constexpr (STAGE == 5) { accum1<8>(h5, accS, accQ); }
            else {
              float z = sB6[0];
              #pragma unroll
              for (int i = 0; i < 8; ++i) z = fmaf(sW6[i], fmaxf(h5[i], 0.f), z);
              p.out[row] = 1.0f / (1.0f + expf(-z));
            }
          }
        }
      }
    }
  }

  if constexpr (STAGE <= 5) {
    const int lane = threadIdx.x & 63;
    const int wv = threadIdx.x >> 6;
    #pragma unroll
    for (int v = 0; v < 2 * W; ++v) {
      float val = (v < W) ? accS[v] : accQ[v - W];
      #pragma unroll
      for (int d = 1; d < 64; d <<= 1) val += __shfl_xor(val, d, 64);
      if (lane == 0) red[wv][v] = val;
    }
    __syncthreads();
    if (threadIdx.x < 2 * W) {
      float f = red[0][threadIdx.x] + red[1][threadIdx.x] +
                red[2][threadIdx.x] + red[3][threadIdx.x];
      const int slot = blockIdx.x & (NSLOT - 1);
      atomicAdd(p.sums + slot * SUMSTRIDE + OFF + threadIdx.x, f);
    }
  }
}

extern "C" void kernel_launch(void* const* d_in, const int* in_sizes, int n_in,
                              void* d_out, int out_size, void* d_ws, size_t ws_size,
                              hipStream_t stream) {
  P p;
  p.in  = (const float*)d_in[0];
  p.w1 = (const float*)d_in[1];  p.b1 = (const float*)d_in[2];
  p.g1 = (const float*)d_in[3];  p.be1 = (const float*)d_in[4];
  p.w2 = (const float*)d_in[5];  p.b2 = (const float*)d_in[6];
  p.g2 = (const float*)d_in[7];  p.be2 = (const float*)d_in[8];
  p.w3 = (const float*)d_in[9];  p.b3 = (const float*)d_in[10];
  p.g3 = (const float*)d_in[11]; p.be3 = (const float*)d_in[12];
  p.w4 = (const float*)d_in[13]; p.b4 = (const float*)d_in[14];
  p.g4 = (const float*)d_in[15]; p.be4 = (const float*)d_in[16];
  p.w5 = (const float*)d_in[17]; p.b5 = (const float*)d_in[18];
  p.g5 = (const float*)d_in[19]; p.be5 = (const float*)d_in[20];
  p.w6 = (const float*)d_in[21]; p.b6 = (const float*)d_in[22];
  p.out = (float*)d_out;
  p.sums = (float*)d_ws;
  p.B = in_sizes[0] / 8;

  hipMemsetAsync(d_ws, 0, NSLOT * SUMSTRIDE * sizeof(float), stream);

  const int grid = (p.B + 255) / 256;   // 8192: one row per thread
  const dim3 block(256);
  qcnn<1><<<grid, block, 0, stream>>>(p);
  qcnn<2><<<grid, block, 0, stream>>>(p);
  qcnn<3><<<grid, block, 0, stream>>>(p);
  qcnn<4><<<grid, block, 0, stream>>>(p);
  qcnn<5><<<grid, block, 0, stream>>>(p);
  qcnn<6><<<grid, block, 0, stream>>>(p);
}

// Round 12
// 631.579 us; speedup vs baseline: 4.7533x; 1.0457x over previous
//
#include <hip/hip_runtime.h>
#include <math.h>

#define EPSBN 1e-5f

// sums layout in d_ws (floats), NSLOT slots of stride SUMSTRIDE:
// 0: s1[16], 16: q1[16], 32: s2[16], 48: q2[16], 64: s3[12], 76: q3[12],
// 88: s4[12], 100: q4[12], 112: s5[8], 120: q5[8]
constexpr int NSLOT = 8;
constexpr int SUMSTRIDE = 128;

struct P {
  const float* in;
  const float *w1,*b1,*g1,*be1;
  const float *w2,*b2,*g2,*be2;
  const float *w3,*b3,*g3,*be3;
  const float *w4,*b4,*g4,*be4;
  const float *w5,*b5,*g5,*be5;
  const float *w6,*b6;
  float* out;
  float* sums;
  int B;
};

__device__ inline float slot_sum(const float* base) {
  float s = 0.f;
  #pragma unroll
  for (int k = 0; k < NSLOT; ++k) s += base[k * SUMSTRIDE];
  return s;
}

// interleaved fold coeffs {a,c} per output into LDS; executed by one wave's low lanes
template<int OUT>
__device__ inline void fold_coeff(float* sf, const float* __restrict__ g,
                                  const float* __restrict__ be,
                                  const float* sum, const float* sq,
                                  float invB, int lane) {
  if (lane < OUT) {
    const int o = lane;
    float m = slot_sum(sum + o) * invB;
    float v = slot_sum(sq + o) * invB - m * m;
    float a = g[o] * rsqrtf(v + EPSBN);
    sf[2 * o]     = a;
    sf[2 * o + 1] = be[o] - a * m;   // bias b stays inside h (raw linear incl. bias)
  }
}

template<int N>
__device__ inline void accum1(const float (&h)[N], float (&aS)[16], float (&aQ)[16]) {
  #pragma unroll
  for (int o = 0; o < N; ++o) {
    aS[o] += h[o];
    aQ[o] = fmaf(h[o], h[o], aQ[o]);
  }
}

// x_next[o] = relu(a*h + c)  (fold applied on activation side)
template<int N>
__device__ inline void bnrelu(const float (&h)[N], const float* sf, float (&xo)[N]) {
  #pragma unroll
  for (int o = 0; o < N; ++o) {
    float2 f = *reinterpret_cast<const float2*>(&sf[2 * o]);
    xo[o] = fmaxf(fmaf(f.x, h[o], f.y), 0.f);
  }
}

template<int STAGE>
__global__ __launch_bounds__(256, 4)
void qcnn(P p) {
  // only fold coefficients + reduction scratch in LDS (weights go via s_load)
  __shared__ alignas(16) float sF1[32], sF2[32], sF3[24], sF4[24], sF5[16];
  __shared__ float red[4][32];

  const float invB = 1.0f / (float)p.B;
  const int lane = threadIdx.x & 63;
  const int wv = threadIdx.x >> 6;
  // distribute per-layer fold computation across the 4 waves (once per block)
  if constexpr (STAGE >= 2) { if (wv == 0) fold_coeff<16>(sF1, p.g1, p.be1, p.sums + 0,   p.sums + 16,  invB, lane); }
  if constexpr (STAGE >= 3) { if (wv == 1) fold_coeff<16>(sF2, p.g2, p.be2, p.sums + 32,  p.sums + 48,  invB, lane); }
  if constexpr (STAGE >= 4) { if (wv == 2) fold_coeff<12>(sF3, p.g3, p.be3, p.sums + 64,  p.sums + 76,  invB, lane); }
  if constexpr (STAGE >= 5) { if (wv == 3) fold_coeff<12>(sF4, p.g4, p.be4, p.sums + 88,  p.sums + 100, invB, lane); }
  if constexpr (STAGE == 6) { if (wv == 1) fold_coeff<8> (sF5, p.g5, p.be5, p.sums + 112, p.sums + 120, invB, lane); }
  if constexpr (STAGE >= 2) __syncthreads();

  constexpr int W   = (STAGE <= 2) ? 16 : (STAGE <= 4) ? 12 : 8;   // stats width
  constexpr int OFF = (STAGE == 1) ? 0 : (STAGE == 2) ? 32 : (STAGE == 3) ? 64
                    : (STAGE == 4) ? 88 : 112;

  float accS[16], accQ[16];
  if constexpr (STAGE <= 5) {
    #pragma unroll
    for (int i = 0; i < 16; ++i) { accS[i] = 0.f; accQ[i] = 0.f; }
  }

  // one row per thread, no loop (avoids LICM weight-hoist spill; R5/R6 lesson)
  const int row = blockIdx.x * 256 + threadIdx.x;
  if (row < p.B) {
    float x[8];
    const float4* ip = reinterpret_cast<const float4*>(p.in) + (size_t)row * 2;
    float4 u0 = ip[0], u1 = ip[1];
    x[0] = u0.x; x[1] = u0.y; x[2] = u0.z; x[3] = u0.w;
    x[4] = u1.x; x[5] = u1.y; x[6] = u1.z; x[7] = u1.w;

    // L1 raw: weights/bias from global (uniform address -> s_load -> SGPR operand)
    float h1[16];
    #pragma unroll
    for (int o = 0; o < 16; ++o) {
      float s = p.b1[o];
      #pragma unroll
      for (int i = 0; i < 8; ++i) s = fmaf(p.w1[o * 8 + i], x[i], s);
      h1[o] = s;
    }
    if constexpr (STAGE == 1) { accum1<16>(h1, accS, accQ); }
    else {
      float x1[16];
      bnrelu<16>(h1, sF1, x1);

      float h2[16];
      #pragma unroll
      for (int o = 0; o < 16; ++o) {
        float s = p.b2[o];
        #pragma unroll
        for (int i = 0; i < 16; ++i) s = fmaf(p.w2[o * 16 + i], x1[i], s);
        h2[o] = s;
      }
      if constexpr (STAGE == 2) { accum1<16>(h2, accS, accQ); }
      else {
        // x2 = relu(bn2) + x1 (outer relu redundant: both terms >= 0)
        float t2[16], x2[16];
        bnrelu<16>(h2, sF2, t2);
        #pragma unroll
        for (int o = 0; o < 16; ++o) x2[o] = t2[o] + x1[o];

        float h3[12];
        #pragma unroll
        for (int o = 0; o < 12; ++o) {
          float s = p.b3[o];
          #pragma unroll
          for (int i = 0; i < 16; ++i) s = fmaf(p.w3[o * 16 + i], x2[i], s);
          h3[o] = s;
        }
        if constexpr (STAGE == 3) { accum1<12>(h3, accS, accQ); }
        else {
          float x3[12];
          bnrelu<12>(h3, sF3, x3);

          float h4[12];
          #pragma unroll
          for (int o = 0; o < 12; ++o) {
            float s = p.b4[o];
            #pragma unroll
            for (int i = 0; i < 12; ++i) s = fmaf(p.w4[o * 12 + i], x3[i], s);
            h4[o] = s;
          }
          if constexpr (STAGE == 4) { accum1<12>(h4, accS, accQ); }
          else {
            float t4[12], x4[12];
            bnrelu<12>(h4, sF4, t4);
            #pragma unroll
            for (int o = 0; o < 12; ++o) x4[o] = t4[o] + x3[o];

            float h5[8];
            #pragma unroll
            for (int o = 0; o < 8; ++o) {
              float s = p.b5[o];
              #pragma unroll
              for (int i = 0; i < 12; ++i) s = fmaf(p.w5[o * 12 + i], x4[i], s);
              h5[o] = s;
            }
            if constexpr (STAGE == 5) { accum1<8>(h5, accS, accQ); }
            else {
              float x5[8];
              bnrelu<8>(h5, sF5, x5);
              float z = p.b6[0];
              #pragma unroll
              for (int i = 0; i < 8; ++i) z = fmaf(p.w6[i], x5[i], z);
              p.out[row] = 1.0f / (1.0f + expf(-z));
            }
          }
        }
      }
    }
  }

  if constexpr (STAGE <= 5) {
    #pragma unroll
    for (int v = 0; v < 2 * W; ++v) {
      float val = (v < W) ? accS[v] : accQ[v - W];
      #pragma unroll
      for (int d = 1; d < 64; d <<= 1) val += __shfl_xor(val, d, 64);
      if (lane == 0) red[wv][v] = val;
    }
    __syncthreads();
    if (threadIdx.x < 2 * W) {
      float f = red[0][threadIdx.x] + red[1][threadIdx.x] +
                red[2][threadIdx.x] + red[3][threadIdx.x];
      const int slot = blockIdx.x & (NSLOT - 1);
      atomicAdd(p.sums + slot * SUMSTRIDE + OFF + threadIdx.x, f);
    }
  }
}

extern "C" void kernel_launch(void* const* d_in, const int* in_sizes, int n_in,
                              void* d_out, int out_size, void* d_ws, size_t ws_size,
                              hipStream_t stream) {
  P p;
  p.in  = (const float*)d_in[0];
  p.w1 = (const float*)d_in[1];  p.b1 = (const float*)d_in[2];
  p.g1 = (const float*)d_in[3];  p.be1 = (const float*)d_in[4];
  p.w2 = (const float*)d_in[5];  p.b2 = (const float*)d_in[6];
  p.g2 = (const float*)d_in[7];  p.be2 = (const float*)d_in[8];
  p.w3 = (const float*)d_in[9];  p.b3 = (const float*)d_in[10];
  p.g3 = (const float*)d_in[11]; p.be3 = (const float*)d_in[12];
  p.w4 = (const float*)d_in[13]; p.b4 = (const float*)d_in[14];
  p.g4 = (const float*)d_in[15]; p.be4 = (const float*)d_in[16];
  p.w5 = (const float*)d_in[17]; p.b5 = (const float*)d_in[18];
  p.g5 = (const float*)d_in[19]; p.be5 = (const float*)d_in[20];
  p.w6 = (const float*)d_in[21]; p.b6 = (const float*)d_in[22];
  p.out = (float*)d_out;
  p.sums = (float*)d_ws;
  p.B = in_sizes[0] / 8;

  hipMemsetAsync(d_ws, 0, NSLOT * SUMSTRIDE * sizeof(float), stream);

  const int grid = (p.B + 255) / 256;   // 8192: one row per thread
  const dim3 block(256);
  qcnn<1><<<grid, block, 0, stream>>>(p);
  qcnn<2><<<grid, block, 0, stream>>>(p);
  qcnn<3><<<grid, block, 0, stream>>>(p);
  qcnn<4><<<grid, block, 0, stream>>>(p);
  qcnn<5><<<grid, block, 0, stream>>>(p);
  qcnn<6><<<grid, block, 0, stream>>>(p);
}

// Round 13
// 621.027 us; speedup vs baseline: 4.8341x; 1.0170x over previous
//
#include <hip/hip_runtime.h>
#include <math.h>

#define EPSBN 1e-5f

// sums layout in d_ws (floats), NSLOT slots of stride SUMSTRIDE:
// 0: s1[16], 16: q1[16], 32: s2[16], 48: q2[16], 64: s3[12], 76: q3[12],
// 88: s4[12], 100: q4[12], 112: s5[8], 120: q5[8]
constexpr int NSLOT = 8;
constexpr int SUMSTRIDE = 128;

struct P {
  const float* in;
  const float *w1,*b1,*g1,*be1;
  const float *w2,*b2,*g2,*be2;
  const float *w3,*b3,*g3,*be3;
  const float *w4,*b4,*g4,*be4;
  const float *w5,*b5,*g5,*be5;
  const float *w6,*b6;
  float* out;
  float* sums;
  int B;
};

__device__ inline float slot_sum(const float* base) {
  float s = 0.f;
  #pragma unroll
  for (int k = 0; k < NSLOT; ++k) s += base[k * SUMSTRIDE];
  return s;
}

// interleaved fold coeffs {a,c} per output into LDS; executed by one wave's low lanes
template<int OUT>
__device__ inline void fold_coeff(float* sf, const float* __restrict__ g,
                                  const float* __restrict__ be,
                                  const float* sum, const float* sq,
                                  float invB, int lane) {
  if (lane < OUT) {
    const int o = lane;
    float m = slot_sum(sum + o) * invB;
    float v = slot_sum(sq + o) * invB - m * m;
    float a = g[o] * rsqrtf(v + EPSBN);
    sf[2 * o]     = a;
    sf[2 * o + 1] = be[o] - a * m;   // bias b stays inside h (raw linear incl. bias)
  }
}

template<int N>
__device__ inline void accum1(const float (&h)[N], float (&aS)[16], float (&aQ)[16]) {
  #pragma unroll
  for (int o = 0; o < N; ++o) {
    aS[o] += h[o];
    aQ[o] = fmaf(h[o], h[o], aQ[o]);
  }
}

// x_next[o] = relu(a*h + c)  (fold applied on activation side)
template<int N>
__device__ inline void bnrelu(const float (&h)[N], const float* sf, float (&xo)[N]) {
  #pragma unroll
  for (int o = 0; o < N; ++o) {
    float2 f = *reinterpret_cast<const float2*>(&sf[2 * o]);
    xo[o] = fmaxf(fmaf(f.x, h[o], f.y), 0.f);
  }
}

template<int STAGE>
__global__ __launch_bounds__(256, 8)   // 8 waves/EU: VGPR<=64 (have ~28) -> 100% occupancy target
void qcnn(P p) {
  // only fold coefficients + reduction scratch in LDS (weights go via s_load)
  __shared__ alignas(16) float sF1[32], sF2[32], sF3[24], sF4[24], sF5[16];
  __shared__ float red[4][32];

  const float invB = 1.0f / (float)p.B;
  const int lane = threadIdx.x & 63;
  const int wv = threadIdx.x >> 6;
  // distribute per-layer fold computation across the 4 waves (once per block)
  if constexpr (STAGE >= 2) { if (wv == 0) fold_coeff<16>(sF1, p.g1, p.be1, p.sums + 0,   p.sums + 16,  invB, lane); }
  if constexpr (STAGE >= 3) { if (wv == 1) fold_coeff<16>(sF2, p.g2, p.be2, p.sums + 32,  p.sums + 48,  invB, lane); }
  if constexpr (STAGE >= 4) { if (wv == 2) fold_coeff<12>(sF3, p.g3, p.be3, p.sums + 64,  p.sums + 76,  invB, lane); }
  if constexpr (STAGE >= 5) { if (wv == 3) fold_coeff<12>(sF4, p.g4, p.be4, p.sums + 88,  p.sums + 100, invB, lane); }
  if constexpr (STAGE == 6) { if (wv == 1) fold_coeff<8> (sF5, p.g5, p.be5, p.sums + 112, p.sums + 120, invB, lane); }
  if constexpr (STAGE >= 2) __syncthreads();

  constexpr int W   = (STAGE <= 2) ? 16 : (STAGE <= 4) ? 12 : 8;   // stats width
  constexpr int OFF = (STAGE == 1) ? 0 : (STAGE == 2) ? 32 : (STAGE == 3) ? 64
                    : (STAGE == 4) ? 88 : 112;

  float accS[16], accQ[16];
  if constexpr (STAGE <= 5) {
    #pragma unroll
    for (int i = 0; i < 16; ++i) { accS[i] = 0.f; accQ[i] = 0.f; }
  }

  // one row per thread, no loop (avoids LICM weight-hoist spill; R5/R6 lesson)
  const int row = blockIdx.x * 256 + threadIdx.x;
  if (row < p.B) {
    float x[8];
    const float4* ip = reinterpret_cast<const float4*>(p.in) + (size_t)row * 2;
    float4 u0 = ip[0], u1 = ip[1];
    x[0] = u0.x; x[1] = u0.y; x[2] = u0.z; x[3] = u0.w;
    x[4] = u1.x; x[5] = u1.y; x[6] = u1.z; x[7] = u1.w;

    // L1 raw: weights/bias from global (uniform address -> s_load -> SGPR operand)
    float h1[16];
    #pragma unroll
    for (int o = 0; o < 16; ++o) {
      float s = p.b1[o];
      #pragma unroll
      for (int i = 0; i < 8; ++i) s = fmaf(p.w1[o * 8 + i], x[i], s);
      h1[o] = s;
    }
    if constexpr (STAGE == 1) { accum1<16>(h1, accS, accQ); }
    else {
      float x1[16];
      bnrelu<16>(h1, sF1, x1);

      float h2[16];
      #pragma unroll
      for (int o = 0; o < 16; ++o) {
        float s = p.b2[o];
        #pragma unroll
        for (int i = 0; i < 16; ++i) s = fmaf(p.w2[o * 16 + i], x1[i], s);
        h2[o] = s;
      }
      if constexpr (STAGE == 2) { accum1<16>(h2, accS, accQ); }
      else {
        // x2 = relu(bn2) + x1 (outer relu redundant: both terms >= 0)
        float t2[16], x2[16];
        bnrelu<16>(h2, sF2, t2);
        #pragma unroll
        for (int o = 0; o < 16; ++o) x2[o] = t2[o] + x1[o];

        float h3[12];
        #pragma unroll
        for (int o = 0; o < 12; ++o) {
          float s = p.b3[o];
          #pragma unroll
          for (int i = 0; i < 16; ++i) s = fmaf(p.w3[o * 16 + i], x2[i], s);
          h3[o] = s;
        }
        if constexpr (STAGE == 3) { accum1<12>(h3, accS, accQ); }
        else {
          float x3[12];
          bnrelu<12>(h3, sF3, x3);

          float h4[12];
          #pragma unroll
          for (int o = 0; o < 12; ++o) {
            float s = p.b4[o];
            #pragma unroll
            for (int i = 0; i < 12; ++i) s = fmaf(p.w4[o * 12 + i], x3[i], s);
            h4[o] = s;
          }
          if constexpr (STAGE == 4) { accum1<12>(h4, accS, accQ); }
          else {
            float t4[12], x4[12];
            bnrelu<12>(h4, sF4, t4);
            #pragma unroll
            for (int o = 0; o < 12; ++o) x4[o] = t4[o] + x3[o];

            float h5[8];
            #pragma unroll
            for (int o = 0; o < 8; ++o) {
              float s = p.b5[o];
              #pragma unroll
              for (int i = 0; i < 12; ++i) s = fmaf(p.w5[o * 12 + i], x4[i], s);
              h5[o] = s;
            }
            if constexpr (STAGE == 5) { accum1<8>(h5, accS, accQ); }
            else {
              float x5[8];
              bnrelu<8>(h5, sF5, x5);
              float z = p.b6[0];
              #pragma unroll
              for (int i = 0; i < 8; ++i) z = fmaf(p.w6[i], x5[i], z);
              p.out[row] = 1.0f / (1.0f + expf(-z));
            }
          }
        }
      }
    }
  }

  if constexpr (STAGE <= 5) {
    #pragma unroll
    for (int v = 0; v < 2 * W; ++v) {
      float val = (v < W) ? accS[v] : accQ[v - W];
      #pragma unroll
      for (int d = 1; d < 64; d <<= 1) val += __shfl_xor(val, d, 64);
      if (lane == 0) red[wv][v] = val;
    }
    __syncthreads();
    if (threadIdx.x < 2 * W) {
      float f = red[0][threadIdx.x] + red[1][threadIdx.x] +
                red[2][threadIdx.x] + red[3][threadIdx.x];
      const int slot = blockIdx.x & (NSLOT - 1);
      atomicAdd(p.sums + slot * SUMSTRIDE + OFF + threadIdx.x, f);
    }
  }
}

extern "C" void kernel_launch(void* const* d_in, const int* in_sizes, int n_in,
                              void* d_out, int out_size, void* d_ws, size_t ws_size,
                              hipStream_t stream) {
  P p;
  p.in  = (const float*)d_in[0];
  p.w1 = (const float*)d_in[1];  p.b1 = (const float*)d_in[2];
  p.g1 = (const float*)d_in[3];  p.be1 = (const float*)d_in[4];
  p.w2 = (const float*)d_in[5];  p.b2 = (const float*)d_in[6];
  p.g2 = (const float*)d_in[7];  p.be2 = (const float*)d_in[8];
  p.w3 = (const float*)d_in[9];  p.b3 = (const float*)d_in[10];
  p.g3 = (const float*)d_in[11]; p.be3 = (const float*)d_in[12];
  p.w4 = (const float*)d_in[13]; p.b4 = (const float*)d_in[14];
  p.g4 = (const float*)d_in[15]; p.be4 = (const float*)d_in[16];
  p.w5 = (const float*)d_in[17]; p.b5 = (const float*)d_in[18];
  p.g5 = (const float*)d_in[19]; p.be5 = (const float*)d_in[20];
  p.w6 = (const float*)d_in[21]; p.b6 = (const float*)d_in[22];
  p.out = (float*)d_out;
  p.sums = (float*)d_ws;
  p.B = in_sizes[0] / 8;

  hipMemsetAsync(d_ws, 0, NSLOT * SUMSTRIDE * sizeof(float), stream);

  const int grid = (p.B + 255) / 256;   // 8192: one row per thread
  const dim3 block(256);
  qcnn<1><<<grid, block, 0, stream>>>(p);
  qcnn<2><<<grid, block, 0, stream>>>(p);
  qcnn<3><<<grid, block, 0, stream>>>(p);
  qcnn<4><<<grid, block, 0, stream>>>(p);
  qcnn<5><<<grid, block, 0, stream>>>(p);
  qcnn<6><<<grid, block, 0, stream>>>(p);
}

// Round 14
// 489.457 us; speedup vs baseline: 6.1335x; 1.2688x over previous
//
#include <hip/hip_runtime.h>
#include <math.h>

#define EPSBN 1e-5f

constexpr int NSLOT = 8;
constexpr int SUMSTRIDE = 128;

struct P {
  const float* in;
  const float *w1,*b1,*g1,*be1;
  const float *w2,*b2,*g2,*be2;
  const float *w3,*b3,*g3,*be3;
  const float *w4,*b4,*g4,*be4;
  const float *w5,*b5,*g5,*be5;
  const float *w6,*b6;
  float* out;
  float* sums;
  int B;
};

__device__ inline float slot_sum(const float* base) {
  float s = 0.f;
  #pragma unroll
  for (int k = 0; k < NSLOT; ++k) s += base[k * SUMSTRIDE];
  return s;
}

template<int OUT>
__device__ inline void fold_coeff(float* sf, const float* __restrict__ g,
                                  const float* __restrict__ be,
                                  const float* sum, const float* sq,
                                  float invB, int lane) {
  if (lane < OUT) {
    const int o = lane;
    float m = slot_sum(sum + o) * invB;
    float v = slot_sum(sq + o) * invB - m * m;
    float a = g[o] * rsqrtf(v + EPSBN);
    sf[2 * o]     = a;
    sf[2 * o + 1] = be[o] - a * m;
  }
}

// accumulate BOTH rows' h into the stats accumulators
template<int N>
__device__ inline void accum2(const float (&h)[2][N], float (&aS)[16], float (&aQ)[16]) {
  #pragma unroll
  for (int o = 0; o < N; ++o) {
    aS[o] += h[0][o] + h[1][o];
    aQ[o] = fmaf(h[0][o], h[0][o], aQ[o]);
    aQ[o] = fmaf(h[1][o], h[1][o], aQ[o]);
  }
}

template<int N>
__device__ inline void bnrelu2(const float (&h)[2][N], const float* sf, float (&xo)[2][N]) {
  #pragma unroll
  for (int o = 0; o < N; ++o) {
    float2 f = *reinterpret_cast<const float2*>(&sf[2 * o]);
    #pragma unroll
    for (int r = 0; r < 2; ++r)
      xo[r][o] = fmaxf(fmaf(f.x, h[r][o], f.y), 0.f);
  }
}

template<int OUT, int IN>
__device__ inline void lin2(const float (&xi)[2][IN], const float* __restrict__ w,
                            const float* __restrict__ b, float (&ho)[2][OUT]) {
  #pragma unroll
  for (int o = 0; o < OUT; ++o) {
    float s0 = b[o], s1 = b[o];
    #pragma unroll
    for (int i = 0; i < IN; ++i) {
      float wv = w[o * IN + i];        // uniform -> s_load -> SGPR operand
      s0 = fmaf(wv, xi[0][i], s0);
      s1 = fmaf(wv, xi[1][i], s1);
    }
    ho[0][o] = s0; ho[1][o] = s1;
  }
}

template<int STAGE>
__global__ __launch_bounds__(256, 6)   // ~85 VGPR cap; peak live ~75 (acc32 + 2x16 act + misc)
void qcnn(P p) {
  __shared__ alignas(16) float sF1[32], sF2[32], sF3[24], sF4[24], sF5[16];
  __shared__ float red[4][32];

  const float invB = 1.0f / (float)p.B;
  const int lane = threadIdx.x & 63;
  const int wv = threadIdx.x >> 6;
  if constexpr (STAGE >= 2) { if (wv == 0) fold_coeff<16>(sF1, p.g1, p.be1, p.sums + 0,   p.sums + 16,  invB, lane); }
  if constexpr (STAGE >= 3) { if (wv == 1) fold_coeff<16>(sF2, p.g2, p.be2, p.sums + 32,  p.sums + 48,  invB, lane); }
  if constexpr (STAGE >= 4) { if (wv == 2) fold_coeff<12>(sF3, p.g3, p.be3, p.sums + 64,  p.sums + 76,  invB, lane); }
  if constexpr (STAGE >= 5) { if (wv == 3) fold_coeff<12>(sF4, p.g4, p.be4, p.sums + 88,  p.sums + 100, invB, lane); }
  if constexpr (STAGE == 6) { if (wv == 1) fold_coeff<8> (sF5, p.g5, p.be5, p.sums + 112, p.sums + 120, invB, lane); }
  if constexpr (STAGE >= 2) __syncthreads();

  constexpr int W   = (STAGE <= 2) ? 16 : (STAGE <= 4) ? 12 : 8;
  constexpr int OFF = (STAGE == 1) ? 0 : (STAGE == 2) ? 32 : (STAGE == 3) ? 64
                    : (STAGE == 4) ? 88 : 112;

  float accS[16], accQ[16];
  if constexpr (STAGE <= 5) {
    #pragma unroll
    for (int i = 0; i < 16; ++i) { accS[i] = 0.f; accQ[i] = 0.f; }
  }

  // two INDEPENDENT rows per thread (row0, row0+B/2): 2x ILP, still loop-free
  const int halfB = p.B >> 1;
  const int row0 = blockIdx.x * 256 + threadIdx.x;
  if (row0 < halfB) {
    const int row1 = row0 + halfB;

    float x[2][8];
    {
      const float4* ip0 = reinterpret_cast<const float4*>(p.in) + (size_t)row0 * 2;
      const float4* ip1 = reinterpret_cast<const float4*>(p.in) + (size_t)row1 * 2;
      float4 a0 = ip0[0], a1 = ip0[1], b0 = ip1[0], b1 = ip1[1];
      x[0][0]=a0.x; x[0][1]=a0.y; x[0][2]=a0.z; x[0][3]=a0.w;
      x[0][4]=a1.x; x[0][5]=a1.y; x[0][6]=a1.z; x[0][7]=a1.w;
      x[1][0]=b0.x; x[1][1]=b0.y; x[1][2]=b0.z; x[1][3]=b0.w;
      x[1][4]=b1.x; x[1][5]=b1.y; x[1][6]=b1.z; x[1][7]=b1.w;
    }

    float h1[2][16];
    lin2<16,8>(x, p.w1, p.b1, h1);
    if constexpr (STAGE == 1) { accum2<16>(h1, accS, accQ); }
    else {
      float x1[2][16];
      bnrelu2<16>(h1, sF1, x1);

      float h2[2][16];
      lin2<16,16>(x1, p.w2, p.b2, h2);
      if constexpr (STAGE == 2) { accum2<16>(h2, accS, accQ); }
      else {
        float x2[2][16];
        bnrelu2<16>(h2, sF2, x2);          // relu(bn2)
        #pragma unroll
        for (int r = 0; r < 2; ++r)
          #pragma unroll
          for (int o = 0; o < 16; ++o) x2[r][o] += x1[r][o];   // outer relu redundant

        float h3[2][12];
        lin2<12,16>(x2, p.w3, p.b3, h3);
        if constexpr (STAGE == 3) { accum2<12>(h3, accS, accQ); }
        else {
          float x3[2][12];
          bnrelu2<12>(h3, sF3, x3);

          float h4[2][12];
          lin2<12,12>(x3, p.w4, p.b4, h4);
          if constexpr (STAGE == 4) { accum2<12>(h4, accS, accQ); }
          else {
            float x4[2][12];
            bnrelu2<12>(h4, sF4, x4);
            #pragma unroll
            for (int r = 0; r < 2; ++r)
              #pragma unroll
              for (int o = 0; o < 12; ++o) x4[r][o] += x3[r][o];

            float h5[2][8];
            lin2<8,12>(x4, p.w5, p.b5, h5);
            if constexpr (STAGE == 5) { accum2<8>(h5, accS, accQ); }
            else {
              float x5[2][8];
              bnrelu2<8>(h5, sF5, x5);
              float z0 = p.b6[0], z1 = p.b6[0];
              #pragma unroll
              for (int i = 0; i < 8; ++i) {
                float wv6 = p.w6[i];
                z0 = fmaf(wv6, x5[0][i], z0);
                z1 = fmaf(wv6, x5[1][i], z1);
              }
              p.out[row0] = 1.0f / (1.0f + expf(-z0));
              p.out[row1] = 1.0f / (1.0f + expf(-z1));
            }
          }
        }
      }
    }
  }

  if constexpr (STAGE <= 5) {
    #pragma unroll
    for (int v = 0; v < 2 * W; ++v) {
      float val = (v < W) ? accS[v] : accQ[v - W];
      #pragma unroll
      for (int d = 1; d < 64; d <<= 1) val += __shfl_xor(val, d, 64);
      if (lane == 0) red[wv][v] = val;
    }
    __syncthreads();
    if (threadIdx.x < 2 * W) {
      float f = red[0][threadIdx.x] + red[1][threadIdx.x] +
                red[2][threadIdx.x] + red[3][threadIdx.x];
      const int slot = blockIdx.x & (NSLOT - 1);
      atomicAdd(p.sums + slot * SUMSTRIDE + OFF + threadIdx.x, f);
    }
  }
}

extern "C" void kernel_launch(void* const* d_in, const int* in_sizes, int n_in,
                              void* d_out, int out_size, void* d_ws, size_t ws_size,
                              hipStream_t stream) {
  P p;
  p.in  = (const float*)d_in[0];
  p.w1 = (const float*)d_in[1];  p.b1 = (const float*)d_in[2];
  p.g1 = (const float*)d_in[3];  p.be1 = (const float*)d_in[4];
  p.w2 = (const float*)d_in[5];  p.b2 = (const float*)d_in[6];
  p.g2 = (const float*)d_in[7];  p.be2 = (const float*)d_in[8];
  p.w3 = (const float*)d_in[9];  p.b3 = (const float*)d_in[10];
  p.g3 = (const float*)d_in[11]; p.be3 = (const float*)d_in[12];
  p.w4 = (const float*)d_in[13]; p.b4 = (const float*)d_in[14];
  p.g4 = (const float*)d_in[15]; p.be4 = (const float*)d_in[16];
  p.w5 = (const float*)d_in[17]; p.b5 = (const float*)d_in[18];
  p.g5 = (const float*)d_in[19]; p.be5 = (const float*)d_in[20];
  p.w6 = (const float*)d_in[21]; p.b6 = (const float*)d_in[22];
  p.out = (float*)d_out;
  p.sums = (float*)d_ws;
  p.B = in_sizes[0] / 8;

  hipMemsetAsync(d_ws, 0, NSLOT * SUMSTRIDE * sizeof(float), stream);

  const int halfB = p.B >> 1;
  const int grid = (halfB + 255) / 256;   // 4096 blocks, 2 rows/thread
  const dim3 block(256);
  qcnn<1><<<grid, block, 0, stream>>>(p);
  qcnn<2><<<grid, block, 0, stream>>>(p);
  qcnn<3><<<grid, block, 0, stream>>>(p);
  qcnn<4><<<grid, block, 0, stream>>>(p);
  qcnn<5><<<grid, block, 0, stream>>>(p);
  qcnn<6><<<grid, block, 0, stream>>>(p);
}